// Round 4
// baseline (150.950 us; speedup 1.0000x reference)
//
#include <hip/hip_runtime.h>
#include <math.h>

#define B_SZ 8
#define T_SZ 2048
#define C_SZ 1024
#define EPSF 1e-6f
#define QSCALE (6.5f / 127.0f)
#define QINV   (127.0f / 6.5f)

typedef float        f32x4 __attribute__((ext_vector_type(4)));
typedef unsigned int u32;
typedef u32          u32x4 __attribute__((ext_vector_type(4)));

// ---------------------------------------------------------------------------
// Shared device helper: logits_part (256 floats) -> sinkhorn -> wgt[B][4].
// Must be called by all 256 threads of a block.
// ---------------------------------------------------------------------------
__device__ __forceinline__ void compute_weights(const float* __restrict__ logits_part,
                                                float lp[256], float lg[32],
                                                float wgt[B_SZ][4], int tid) {
    lp[tid] = logits_part[tid];
    __syncthreads();
    if (tid < 32) {
        float s = 0.f;
#pragma unroll
        for (int g = 0; g < 8; ++g) s += lp[tid * 8 + g];
        lg[tid] = s;               // logits[b*4+k]
    }
    __syncthreads();
    if (tid < B_SZ) {
        int b = tid;
        float L[4];
#pragma unroll
        for (int i = 0; i < 4; ++i) L[i] = lg[b * 4 + i];
        float mx = fmaxf(fmaxf(L[0], L[1]), fmaxf(L[2], L[3]));
        float m = 2.0f * mx;
        float t[4][4];
#pragma unroll
        for (int i = 0; i < 4; ++i)
#pragma unroll
            for (int j = 0; j < 4; ++j)
                t[i][j] = fmaxf(expf(L[i] + L[j] - m), EPSF);
#pragma unroll
        for (int it = 0; it < 5; ++it) {
#pragma unroll
            for (int i = 0; i < 4; ++i) {
                float rs = t[i][0] + t[i][1] + t[i][2] + t[i][3] + EPSF;
#pragma unroll
                for (int j = 0; j < 4; ++j) t[i][j] /= rs;
            }
#pragma unroll
            for (int j = 0; j < 4; ++j) {
                float cs = t[0][j] + t[1][j] + t[2][j] + t[3][j] + EPSF;
#pragma unroll
                for (int i = 0; i < 4; ++i) t[i][j] /= cs;
            }
        }
#pragma unroll
        for (int i = 0; i < 4; ++i) {
            float rs = t[i][0] + t[i][1] + t[i][2] + t[i][3] + EPSF;
#pragma unroll
            for (int j = 0; j < 4; ++j) t[i][j] /= rs;
        }
        float w[4];
#pragma unroll
        for (int j = 0; j < 4; ++j)
            w[j] = 0.25f * (t[0][j] + t[1][j] + t[2][j] + t[3][j]);
        float s = w[0] + w[1] + w[2] + w[3] + EPSF;
#pragma unroll
        for (int j = 0; j < 4; ++j) w[j] /= s;
        bool fin = isfinite(w[0]) && isfinite(w[1]) && isfinite(w[2]) && isfinite(w[3]);
#pragma unroll
        for (int j = 0; j < 4; ++j)
            wgt[b][j] = fin ? w[j] : 0.25f;
    }
    __syncthreads();
}

// ---------------------------------------------------------------------------
// Kernel 1 (fast path): partial mean over T + int8 quantized copy.
// grid = tseg*32 blocks, 256 threads. Nontemporal branch loads (protect L3
// residency of the int8 copy); regular (allocating) stores for the copy.
// ---------------------------------------------------------------------------
__global__ void pool_quant(const float* __restrict__ br,
                           float* __restrict__ part,
                           u32* __restrict__ qs,
                           int tchunk) {
    int chunk = blockIdx.x & 31;   // b*4 + k
    int seg   = blockIdx.x >> 5;
    int b = chunk >> 2;
    int k = chunk & 3;
    int t0 = seg * tchunk;

    const f32x4* src = (const f32x4*)(br + (size_t)(k * B_SZ + b) * T_SZ * C_SZ);
    u32* qdst = qs + (size_t)(k * B_SZ + b) * T_SZ * (C_SZ / 4);
    int c4 = threadIdx.x;          // 0..255 covers C/4
    f32x4 acc = (f32x4)(0.f);
    for (int t = t0; t < t0 + tchunk; ++t) {
        f32x4 v = __builtin_nontemporal_load(&src[(size_t)t * (C_SZ / 4) + c4]);
        acc += v;
        f32x4 q = v * QINV;
        int q0 = (int)rintf(fminf(fmaxf(q.x, -127.f), 127.f));
        int q1 = (int)rintf(fminf(fmaxf(q.y, -127.f), 127.f));
        int q2 = (int)rintf(fminf(fmaxf(q.z, -127.f), 127.f));
        int q3 = (int)rintf(fminf(fmaxf(q.w, -127.f), 127.f));
        u32 p = (u32)(q0 & 255) | ((u32)(q1 & 255) << 8) |
                ((u32)(q2 & 255) << 16) | ((u32)(q3 & 255) << 24);
        qdst[(size_t)t * (C_SZ / 4) + c4] = p;
    }
    f32x4* dst = (f32x4*)(part + ((size_t)seg * 32 + chunk) * C_SZ);
    dst[c4] = acc;
}

// ---------------------------------------------------------------------------
// Kernel 1 (fallback): partial mean only (round-3 version).
// ---------------------------------------------------------------------------
__global__ void pool_partial(const float* __restrict__ br,
                             float* __restrict__ part,
                             int tchunk) {
    int chunk = blockIdx.x & 31;
    int seg   = blockIdx.x >> 5;
    int b = chunk >> 2;
    int k = chunk & 3;
    int t0 = seg * tchunk;

    const f32x4* src = (const f32x4*)(br + (size_t)(k * B_SZ + b) * T_SZ * C_SZ);
    int c4 = threadIdx.x;
    f32x4 acc = (f32x4)(0.f);
#pragma unroll 4
    for (int t = t0; t < t0 + tchunk; ++t) {
        acc += src[(size_t)t * (C_SZ / 4) + c4];
    }
    f32x4* dst = (f32x4*)(part + ((size_t)seg * 32 + chunk) * C_SZ);
    dst[c4] = acc;
}

// ---------------------------------------------------------------------------
// Kernel 2: finish pooling + h = tanh(pooled @ w_proj^T) * w_out -> partial
// logits. grid = 256 blocks (chunk = bid>>3, hgroup = bid&7).
// ---------------------------------------------------------------------------
__global__ void proj_logits(const float* __restrict__ part,
                            const float* __restrict__ w_proj,
                            const float* __restrict__ w_out,
                            float* __restrict__ logits_part,
                            int tseg) {
    __shared__ float pooled[C_SZ];
    __shared__ float red[32];
    int bid   = blockIdx.x;
    int chunk = bid >> 3;
    int hg    = bid & 7;
    int tid   = threadIdx.x;

    f32x4 acc = (f32x4)(0.f);
    for (int seg = 0; seg < tseg; ++seg) {
        acc += ((const f32x4*)(part + ((size_t)seg * 32 + chunk) * C_SZ))[tid];
    }
    const float inv = 1.0f / (float)T_SZ;
    ((f32x4*)pooled)[tid] = acc * inv;
    __syncthreads();

    int h   = hg * 32 + (tid >> 3);
    int sub = tid & 7;
    const f32x4* wrow = (const f32x4*)(w_proj + (size_t)h * C_SZ);
    const f32x4* pl   = (const f32x4*)pooled;
    float dot = 0.f;
#pragma unroll 8
    for (int j = 0; j < 32; ++j) {
        int c4 = sub * 32 + j;
        f32x4 w = wrow[c4];
        f32x4 p = pl[c4];
        f32x4 m = w * p;
        dot += m.x + m.y + m.z + m.w;
    }
    dot += __shfl_xor(dot, 1, 64);
    dot += __shfl_xor(dot, 2, 64);
    dot += __shfl_xor(dot, 4, 64);
    if (sub == 0) red[tid >> 3] = tanhf(dot) * w_out[h];
    __syncthreads();
    if (tid == 0) {
        float s = 0.f;
        for (int i = 0; i < 32; ++i) s += red[i];
        logits_part[chunk * 8 + hg] = s;
    }
}

// ---------------------------------------------------------------------------
// Kernel 3 (fast path): weights from logits_part, then blend from the int8
// copy (64 MiB, L3-resident). Each thread handles 16 consecutive c per iter.
// ---------------------------------------------------------------------------
__global__ void mix_q(const u32* __restrict__ qs,
                      const float* __restrict__ logits_part,
                      float* __restrict__ out) {
    __shared__ float lp[256];
    __shared__ float lg[32];
    __shared__ float wgt[B_SZ][4];
    int tid = threadIdx.x;
    compute_weights(logits_part, lp, lg, wgt, tid);

    const size_t n16tot = (size_t)B_SZ * T_SZ * C_SZ / 16;  // 1,048,576
    const u32x4* base = (const u32x4*)qs;
    f32x4* dst = (f32x4*)out;
    for (size_t n = (size_t)blockIdx.x * blockDim.x + tid;
         n < n16tot;
         n += (size_t)gridDim.x * blockDim.x) {
        int b = (int)(n >> 17);                 // T*C/16 = 2^17
        size_t r = n & ((1u << 17) - 1);
        float w0 = wgt[b][0] * QSCALE;
        float w1 = wgt[b][1] * QSCALE;
        float w2 = wgt[b][2] * QSCALE;
        float w3 = wgt[b][3] * QSCALE;
        u32x4 a0 = base[((size_t)(0 * B_SZ + b) << 17) + r];
        u32x4 a1 = base[((size_t)(1 * B_SZ + b) << 17) + r];
        u32x4 a2 = base[((size_t)(2 * B_SZ + b) << 17) + r];
        u32x4 a3 = base[((size_t)(3 * B_SZ + b) << 17) + r];
#pragma unroll
        for (int j = 0; j < 4; ++j) {
            u32 x0 = a0[j], x1 = a1[j], x2 = a2[j], x3 = a3[j];
            f32x4 o;
#pragma unroll
            for (int i = 0; i < 4; ++i) {
                float e0 = (float)(signed char)((x0 >> (8 * i)) & 0xFF);
                float e1 = (float)(signed char)((x1 >> (8 * i)) & 0xFF);
                float e2 = (float)(signed char)((x2 >> (8 * i)) & 0xFF);
                float e3 = (float)(signed char)((x3 >> (8 * i)) & 0xFF);
                o[i] = w0 * e0 + w1 * e1 + w2 * e2 + w3 * e3;
            }
            __builtin_nontemporal_store(o, &dst[n * 4 + j]);
        }
    }
}

// ---------------------------------------------------------------------------
// Kernel 3 (fallback): fp32 blend straight from branches (round-3 version).
// ---------------------------------------------------------------------------
__global__ void mix_kernel(const float* __restrict__ br,
                           const float* __restrict__ logits_part,
                           float* __restrict__ out) {
    __shared__ float lp[256];
    __shared__ float lg[32];
    __shared__ float wgt[B_SZ][4];
    int tid = threadIdx.x;
    compute_weights(logits_part, lp, lg, wgt, tid);

    const size_t n4total = (size_t)B_SZ * T_SZ * C_SZ / 4;
    const size_t btc4 = (size_t)T_SZ * C_SZ / 4;            // 2^19
    const f32x4* src = (const f32x4*)br;
    f32x4* dst = (f32x4*)out;
    for (size_t n = (size_t)blockIdx.x * blockDim.x + tid;
         n < n4total;
         n += (size_t)gridDim.x * blockDim.x) {
        int b = (int)(n >> 19);
        size_t r = n & (btc4 - 1);
        float w0 = wgt[b][0], w1 = wgt[b][1], w2 = wgt[b][2], w3 = wgt[b][3];
        f32x4 v0 = src[((size_t)(0 * B_SZ + b)) * btc4 + r];
        f32x4 v1 = src[((size_t)(1 * B_SZ + b)) * btc4 + r];
        f32x4 v2 = src[((size_t)(2 * B_SZ + b)) * btc4 + r];
        f32x4 v3 = src[((size_t)(3 * B_SZ + b)) * btc4 + r];
        f32x4 o = w0 * v0 + w1 * v1 + w2 * v2 + w3 * v3;
        __builtin_nontemporal_store(o, &dst[n]);
    }
}

extern "C" void kernel_launch(void* const* d_in, const int* in_sizes, int n_in,
                              void* d_out, int out_size, void* d_ws, size_t ws_size,
                              hipStream_t stream) {
    const float* branches = (const float*)d_in[0];
    const float* w_proj   = (const float*)d_in[1];
    const float* w_out    = (const float*)d_in[2];
    float* out = (float*)d_out;

    const size_t qs_words = (size_t)4 * B_SZ * T_SZ * (C_SZ / 4);  // 16,777,216 u32 = 64 MiB
    const size_t part_need = (size_t)32 * 32 * C_SZ;               // tseg=32 partials (floats)
    size_t fast_need = qs_words * sizeof(u32) + (part_need + 256) * sizeof(float);

    if (ws_size >= fast_need) {
        int tseg = 32, tchunk = T_SZ / tseg;
        u32*   qs          = (u32*)d_ws;
        float* part        = (float*)(qs + qs_words);
        float* logits_part = part + part_need;

        pool_quant<<<tseg * 32, 256, 0, stream>>>(branches, part, qs, tchunk);
        proj_logits<<<256, 256, 0, stream>>>(part, w_proj, w_out, logits_part, tseg);
        mix_q<<<2048, 256, 0, stream>>>(qs, logits_part, out);
    } else {
        float* ws = (float*)d_ws;
        int tseg = 32;
        while (tseg > 1 &&
               ((size_t)tseg * 32 * C_SZ + 256) * sizeof(float) > ws_size)
            tseg >>= 1;
        int tchunk = T_SZ / tseg;
        float* part        = ws;
        float* logits_part = ws + (size_t)tseg * 32 * C_SZ;

        pool_partial<<<tseg * 32, 256, 0, stream>>>(branches, part, tchunk);
        proj_logits<<<256, 256, 0, stream>>>(part, w_proj, w_out, logits_part, tseg);
        mix_kernel<<<2048, 256, 0, stream>>>(branches, logits_part, out);
    }
}

// Round 5
// 145.992 us; speedup vs baseline: 1.0340x; 1.0340x over previous
//
#include <hip/hip_runtime.h>
#include <math.h>

#define B_SZ 8
#define T_SZ 2048
#define C_SZ 1024
#define EPSF 1e-6f
#define QSCALE (6.5f / 127.0f)
#define QINV   (127.0f / 6.5f)

typedef float        f32x4 __attribute__((ext_vector_type(4)));
typedef unsigned int u32;
typedef u32          u32x4 __attribute__((ext_vector_type(4)));

// ---------------------------------------------------------------------------
// logits_part (256 floats) -> sinkhorn -> wgt[B][4]. Call with all 256 thr.
// ---------------------------------------------------------------------------
__device__ __forceinline__ void compute_weights(const float* __restrict__ logits_part,
                                                float lp[256], float lg[32],
                                                float wgt[B_SZ][4], int tid) {
    lp[tid] = logits_part[tid];
    __syncthreads();
    if (tid < 32) {
        float s = 0.f;
#pragma unroll
        for (int g = 0; g < 8; ++g) s += lp[tid * 8 + g];
        lg[tid] = s;               // logits[b*4+k]
    }
    __syncthreads();
    if (tid < B_SZ) {
        int b = tid;
        float L[4];
#pragma unroll
        for (int i = 0; i < 4; ++i) L[i] = lg[b * 4 + i];
        float mx = fmaxf(fmaxf(L[0], L[1]), fmaxf(L[2], L[3]));
        float m = 2.0f * mx;
        float t[4][4];
#pragma unroll
        for (int i = 0; i < 4; ++i)
#pragma unroll
            for (int j = 0; j < 4; ++j)
                t[i][j] = fmaxf(expf(L[i] + L[j] - m), EPSF);
#pragma unroll
        for (int it = 0; it < 5; ++it) {
#pragma unroll
            for (int i = 0; i < 4; ++i) {
                float rs = t[i][0] + t[i][1] + t[i][2] + t[i][3] + EPSF;
#pragma unroll
                for (int j = 0; j < 4; ++j) t[i][j] /= rs;
            }
#pragma unroll
            for (int j = 0; j < 4; ++j) {
                float cs = t[0][j] + t[1][j] + t[2][j] + t[3][j] + EPSF;
#pragma unroll
                for (int i = 0; i < 4; ++i) t[i][j] /= cs;
            }
        }
#pragma unroll
        for (int i = 0; i < 4; ++i) {
            float rs = t[i][0] + t[i][1] + t[i][2] + t[i][3] + EPSF;
#pragma unroll
            for (int j = 0; j < 4; ++j) t[i][j] /= rs;
        }
        float w[4];
#pragma unroll
        for (int j = 0; j < 4; ++j)
            w[j] = 0.25f * (t[0][j] + t[1][j] + t[2][j] + t[3][j]);
        float s = w[0] + w[1] + w[2] + w[3] + EPSF;
#pragma unroll
        for (int j = 0; j < 4; ++j) w[j] /= s;
        bool fin = isfinite(w[0]) && isfinite(w[1]) && isfinite(w[2]) && isfinite(w[3]);
#pragma unroll
        for (int j = 0; j < 4; ++j)
            wgt[b][j] = fin ? w[j] : 0.25f;
    }
    __syncthreads();
}

__device__ __forceinline__ u32 quant4(f32x4 v) {
    f32x4 q = v * QINV;
    int q0 = (int)rintf(fminf(fmaxf(q.x, -127.f), 127.f));
    int q1 = (int)rintf(fminf(fmaxf(q.y, -127.f), 127.f));
    int q2 = (int)rintf(fminf(fmaxf(q.z, -127.f), 127.f));
    int q3 = (int)rintf(fminf(fmaxf(q.w, -127.f), 127.f));
    return (u32)(q0 & 255) | ((u32)(q1 & 255) << 8) |
           ((u32)(q2 & 255) << 16) | ((u32)(q3 & 255) << 24);
}

// ---------------------------------------------------------------------------
// Kernel 1 (fast path): partial mean over T + int8 quantized copy.
// grid = tseg*32 blocks, 256 threads. Regular cached loads; explicit 2-wide
// ILP + unroll so loads pipeline (round-4 lesson: un-unrolled load->use->store
// chain serialized on vmcnt).
// ---------------------------------------------------------------------------
__global__ void pool_quant(const float* __restrict__ br,
                           float* __restrict__ part,
                           u32* __restrict__ qs,
                           int tchunk) {
    int chunk = blockIdx.x & 31;   // b*4 + k
    int seg   = blockIdx.x >> 5;
    int b = chunk >> 2;
    int k = chunk & 3;
    int t0 = seg * tchunk;

    const f32x4* src = (const f32x4*)(br + (size_t)(k * B_SZ + b) * T_SZ * C_SZ);
    u32* qdst = qs + (size_t)(k * B_SZ + b) * T_SZ * (C_SZ / 4);
    int c4 = threadIdx.x;          // 0..255 covers C/4
    f32x4 acc0 = (f32x4)(0.f);
    f32x4 acc1 = (f32x4)(0.f);
#pragma unroll 2
    for (int t = t0; t < t0 + tchunk; t += 2) {
        f32x4 v0 = src[(size_t)t * (C_SZ / 4) + c4];
        f32x4 v1 = src[(size_t)(t + 1) * (C_SZ / 4) + c4];
        acc0 += v0;
        acc1 += v1;
        qdst[(size_t)t * (C_SZ / 4) + c4]       = quant4(v0);
        qdst[(size_t)(t + 1) * (C_SZ / 4) + c4] = quant4(v1);
    }
    f32x4* dst = (f32x4*)(part + ((size_t)seg * 32 + chunk) * C_SZ);
    dst[c4] = acc0 + acc1;
}

// ---------------------------------------------------------------------------
// Kernel 1 (fallback): partial mean only (round-3 version).
// ---------------------------------------------------------------------------
__global__ void pool_partial(const float* __restrict__ br,
                             float* __restrict__ part,
                             int tchunk) {
    int chunk = blockIdx.x & 31;
    int seg   = blockIdx.x >> 5;
    int b = chunk >> 2;
    int k = chunk & 3;
    int t0 = seg * tchunk;

    const f32x4* src = (const f32x4*)(br + (size_t)(k * B_SZ + b) * T_SZ * C_SZ);
    int c4 = threadIdx.x;
    f32x4 acc = (f32x4)(0.f);
#pragma unroll 4
    for (int t = t0; t < t0 + tchunk; ++t) {
        acc += src[(size_t)t * (C_SZ / 4) + c4];
    }
    f32x4* dst = (f32x4*)(part + ((size_t)seg * 32 + chunk) * C_SZ);
    dst[c4] = acc;
}

// ---------------------------------------------------------------------------
// Kernel 2: finish pooling + h = tanh(pooled @ w_proj^T) * w_out -> partial
// logits. grid = 256 blocks (chunk = bid>>3, hgroup = bid&7).
// ---------------------------------------------------------------------------
__global__ void proj_logits(const float* __restrict__ part,
                            const float* __restrict__ w_proj,
                            const float* __restrict__ w_out,
                            float* __restrict__ logits_part,
                            int tseg) {
    __shared__ float pooled[C_SZ];
    __shared__ float red[32];
    int bid   = blockIdx.x;
    int chunk = bid >> 3;
    int hg    = bid & 7;
    int tid   = threadIdx.x;

    f32x4 acc = (f32x4)(0.f);
    for (int seg = 0; seg < tseg; ++seg) {
        acc += ((const f32x4*)(part + ((size_t)seg * 32 + chunk) * C_SZ))[tid];
    }
    const float inv = 1.0f / (float)T_SZ;
    ((f32x4*)pooled)[tid] = acc * inv;
    __syncthreads();

    int h   = hg * 32 + (tid >> 3);
    int sub = tid & 7;
    const f32x4* wrow = (const f32x4*)(w_proj + (size_t)h * C_SZ);
    const f32x4* pl   = (const f32x4*)pooled;
    float dot = 0.f;
#pragma unroll 8
    for (int j = 0; j < 32; ++j) {
        int c4 = sub * 32 + j;
        f32x4 w = wrow[c4];
        f32x4 p = pl[c4];
        f32x4 m = w * p;
        dot += m.x + m.y + m.z + m.w;
    }
    dot += __shfl_xor(dot, 1, 64);
    dot += __shfl_xor(dot, 2, 64);
    dot += __shfl_xor(dot, 4, 64);
    if (sub == 0) red[tid >> 3] = tanhf(dot) * w_out[h];
    __syncthreads();
    if (tid == 0) {
        float s = 0.f;
        for (int i = 0; i < 32; ++i) s += red[i];
        logits_part[chunk * 8 + hg] = s;
    }
}

// ---------------------------------------------------------------------------
// Kernel 3 (fast path): weights, then blend from the int8 copy.
// ---------------------------------------------------------------------------
__global__ void mix_q(const u32* __restrict__ qs,
                      const float* __restrict__ logits_part,
                      float* __restrict__ out) {
    __shared__ float lp[256];
    __shared__ float lg[32];
    __shared__ float wgt[B_SZ][4];
    int tid = threadIdx.x;
    compute_weights(logits_part, lp, lg, wgt, tid);

    const size_t n16tot = (size_t)B_SZ * T_SZ * C_SZ / 16;  // 1,048,576
    const u32x4* base = (const u32x4*)qs;
    f32x4* dst = (f32x4*)out;
    for (size_t n = (size_t)blockIdx.x * blockDim.x + tid;
         n < n16tot;
         n += (size_t)gridDim.x * blockDim.x) {
        int b = (int)(n >> 17);                 // T*C/16 = 2^17
        size_t r = n & ((1u << 17) - 1);
        float w0 = wgt[b][0] * QSCALE;
        float w1 = wgt[b][1] * QSCALE;
        float w2 = wgt[b][2] * QSCALE;
        float w3 = wgt[b][3] * QSCALE;
        u32x4 a0 = base[((size_t)(0 * B_SZ + b) << 17) + r];
        u32x4 a1 = base[((size_t)(1 * B_SZ + b) << 17) + r];
        u32x4 a2 = base[((size_t)(2 * B_SZ + b) << 17) + r];
        u32x4 a3 = base[((size_t)(3 * B_SZ + b) << 17) + r];
#pragma unroll
        for (int j = 0; j < 4; ++j) {
            u32 x0 = a0[j], x1 = a1[j], x2 = a2[j], x3 = a3[j];
            f32x4 o;
#pragma unroll
            for (int i = 0; i < 4; ++i) {
                float e0 = (float)(signed char)((x0 >> (8 * i)) & 0xFF);
                float e1 = (float)(signed char)((x1 >> (8 * i)) & 0xFF);
                float e2 = (float)(signed char)((x2 >> (8 * i)) & 0xFF);
                float e3 = (float)(signed char)((x3 >> (8 * i)) & 0xFF);
                o[i] = w0 * e0 + w1 * e1 + w2 * e2 + w3 * e3;
            }
            __builtin_nontemporal_store(o, &dst[n * 4 + j]);
        }
    }
}

// ---------------------------------------------------------------------------
// Kernel 3 (fallback): fp32 blend straight from branches (round-3 version).
// ---------------------------------------------------------------------------
__global__ void mix_kernel(const float* __restrict__ br,
                           const float* __restrict__ logits_part,
                           float* __restrict__ out) {
    __shared__ float lp[256];
    __shared__ float lg[32];
    __shared__ float wgt[B_SZ][4];
    int tid = threadIdx.x;
    compute_weights(logits_part, lp, lg, wgt, tid);

    const size_t n4total = (size_t)B_SZ * T_SZ * C_SZ / 4;
    const size_t btc4 = (size_t)T_SZ * C_SZ / 4;            // 2^19
    const f32x4* src = (const f32x4*)br;
    f32x4* dst = (f32x4*)out;
    for (size_t n = (size_t)blockIdx.x * blockDim.x + tid;
         n < n4total;
         n += (size_t)gridDim.x * blockDim.x) {
        int b = (int)(n >> 19);
        size_t r = n & (btc4 - 1);
        float w0 = wgt[b][0], w1 = wgt[b][1], w2 = wgt[b][2], w3 = wgt[b][3];
        f32x4 v0 = src[((size_t)(0 * B_SZ + b)) * btc4 + r];
        f32x4 v1 = src[((size_t)(1 * B_SZ + b)) * btc4 + r];
        f32x4 v2 = src[((size_t)(2 * B_SZ + b)) * btc4 + r];
        f32x4 v3 = src[((size_t)(3 * B_SZ + b)) * btc4 + r];
        f32x4 o = w0 * v0 + w1 * v1 + w2 * v2 + w3 * v3;
        __builtin_nontemporal_store(o, &dst[n]);
    }
}

extern "C" void kernel_launch(void* const* d_in, const int* in_sizes, int n_in,
                              void* d_out, int out_size, void* d_ws, size_t ws_size,
                              hipStream_t stream) {
    const float* branches = (const float*)d_in[0];
    const float* w_proj   = (const float*)d_in[1];
    const float* w_out    = (const float*)d_in[2];
    float* out = (float*)d_out;

    const size_t qs_words = (size_t)4 * B_SZ * T_SZ * (C_SZ / 4);  // 64 MiB
    const size_t part_need = (size_t)32 * 32 * C_SZ;               // tseg=32 partials
    size_t fast_need = qs_words * sizeof(u32) + (part_need + 256) * sizeof(float);

    if (ws_size >= fast_need) {
        int tseg = 32, tchunk = T_SZ / tseg;
        u32*   qs          = (u32*)d_ws;
        float* part        = (float*)(qs + qs_words);
        float* logits_part = part + part_need;

        pool_quant<<<tseg * 32, 256, 0, stream>>>(branches, part, qs, tchunk);
        proj_logits<<<256, 256, 0, stream>>>(part, w_proj, w_out, logits_part, tseg);
        mix_q<<<2048, 256, 0, stream>>>(qs, logits_part, out);
    } else {
        float* ws = (float*)d_ws;
        int tseg = 32;
        while (tseg > 1 &&
               ((size_t)tseg * 32 * C_SZ + 256) * sizeof(float) > ws_size)
            tseg >>= 1;
        int tchunk = T_SZ / tseg;
        float* part        = ws;
        float* logits_part = ws + (size_t)tseg * 32 * C_SZ;

        pool_partial<<<tseg * 32, 256, 0, stream>>>(branches, part, tchunk);
        proj_logits<<<256, 256, 0, stream>>>(part, w_proj, w_out, logits_part, tseg);
        mix_kernel<<<2048, 256, 0, stream>>>(branches, logits_part, out);
    }
}

// Round 6
// 116.091 us; speedup vs baseline: 1.3003x; 1.2576x over previous
//
#include <hip/hip_runtime.h>
#include <math.h>

#define B_SZ 8
#define T_SZ 2048
#define C_SZ 1024
#define EPSF 1e-6f
#define QSCALE (6.5f / 127.0f)
#define QINV   (127.0f / 6.5f)

typedef float        f32x4 __attribute__((ext_vector_type(4)));
typedef unsigned int u32;

// ---------------------------------------------------------------------------
// logits_part (256 floats) -> sinkhorn -> wgt[B][4]. Call with all 256 thr.
// ---------------------------------------------------------------------------
__device__ __forceinline__ void compute_weights(const float* __restrict__ logits_part,
                                                float lp[256], float lg[32],
                                                float wgt[B_SZ][4], int tid) {
    lp[tid] = logits_part[tid];
    __syncthreads();
    if (tid < 32) {
        float s = 0.f;
#pragma unroll
        for (int g = 0; g < 8; ++g) s += lp[tid * 8 + g];
        lg[tid] = s;               // logits[b*4+k]
    }
    __syncthreads();
    if (tid < B_SZ) {
        int b = tid;
        float L[4];
#pragma unroll
        for (int i = 0; i < 4; ++i) L[i] = lg[b * 4 + i];
        float mx = fmaxf(fmaxf(L[0], L[1]), fmaxf(L[2], L[3]));
        float m = 2.0f * mx;
        float t[4][4];
#pragma unroll
        for (int i = 0; i < 4; ++i)
#pragma unroll
            for (int j = 0; j < 4; ++j)
                t[i][j] = fmaxf(expf(L[i] + L[j] - m), EPSF);
#pragma unroll
        for (int it = 0; it < 5; ++it) {
#pragma unroll
            for (int i = 0; i < 4; ++i) {
                float rs = t[i][0] + t[i][1] + t[i][2] + t[i][3] + EPSF;
#pragma unroll
                for (int j = 0; j < 4; ++j) t[i][j] /= rs;
            }
#pragma unroll
            for (int j = 0; j < 4; ++j) {
                float cs = t[0][j] + t[1][j] + t[2][j] + t[3][j] + EPSF;
#pragma unroll
                for (int i = 0; i < 4; ++i) t[i][j] /= cs;
            }
        }
#pragma unroll
        for (int i = 0; i < 4; ++i) {
            float rs = t[i][0] + t[i][1] + t[i][2] + t[i][3] + EPSF;
#pragma unroll
            for (int j = 0; j < 4; ++j) t[i][j] /= rs;
        }
        float w[4];
#pragma unroll
        for (int j = 0; j < 4; ++j)
            w[j] = 0.25f * (t[0][j] + t[1][j] + t[2][j] + t[3][j]);
        float s = w[0] + w[1] + w[2] + w[3] + EPSF;
#pragma unroll
        for (int j = 0; j < 4; ++j) w[j] /= s;
        bool fin = isfinite(w[0]) && isfinite(w[1]) && isfinite(w[2]) && isfinite(w[3]);
#pragma unroll
        for (int j = 0; j < 4; ++j)
            wgt[b][j] = fin ? w[j] : 0.25f;
    }
    __syncthreads();
}

__device__ __forceinline__ u32 quant4(f32x4 v) {
    f32x4 q = v * QINV;
    int q0 = (int)rintf(fminf(fmaxf(q.x, -127.f), 127.f));
    int q1 = (int)rintf(fminf(fmaxf(q.y, -127.f), 127.f));
    int q2 = (int)rintf(fminf(fmaxf(q.z, -127.f), 127.f));
    int q3 = (int)rintf(fminf(fmaxf(q.w, -127.f), 127.f));
    return (u32)(q0 & 255) | ((u32)(q1 & 255) << 8) |
           ((u32)(q2 & 255) << 16) | ((u32)(q3 & 255) << 24);
}

// ---------------------------------------------------------------------------
// Kernel 1 (fast path): partial mean over T + int8 quantized copy.
// grid = tseg*32 blocks, 256 threads. Regular cached loads, 2-wide ILP.
// qs stores: 4 B/lane, 256 B/wave contiguous (full cache lines per wave).
// ---------------------------------------------------------------------------
__global__ void pool_quant(const float* __restrict__ br,
                           float* __restrict__ part,
                           u32* __restrict__ qs,
                           int tchunk) {
    int chunk = blockIdx.x & 31;   // b*4 + k
    int seg   = blockIdx.x >> 5;
    int b = chunk >> 2;
    int k = chunk & 3;
    int t0 = seg * tchunk;

    const f32x4* src = (const f32x4*)(br + (size_t)(k * B_SZ + b) * T_SZ * C_SZ);
    u32* qdst = qs + (size_t)(k * B_SZ + b) * T_SZ * (C_SZ / 4);
    int c4 = threadIdx.x;          // 0..255 covers C/4
    f32x4 acc0 = (f32x4)(0.f);
    f32x4 acc1 = (f32x4)(0.f);
#pragma unroll 2
    for (int t = t0; t < t0 + tchunk; t += 2) {
        f32x4 v0 = src[(size_t)t * (C_SZ / 4) + c4];
        f32x4 v1 = src[(size_t)(t + 1) * (C_SZ / 4) + c4];
        acc0 += v0;
        acc1 += v1;
        qdst[(size_t)t * (C_SZ / 4) + c4]       = quant4(v0);
        qdst[(size_t)(t + 1) * (C_SZ / 4) + c4] = quant4(v1);
    }
    f32x4* dst = (f32x4*)(part + ((size_t)seg * 32 + chunk) * C_SZ);
    dst[c4] = acc0 + acc1;
}

// ---------------------------------------------------------------------------
// Kernel 1 (fallback): partial mean only (round-3 version).
// ---------------------------------------------------------------------------
__global__ void pool_partial(const float* __restrict__ br,
                             float* __restrict__ part,
                             int tchunk) {
    int chunk = blockIdx.x & 31;
    int seg   = blockIdx.x >> 5;
    int b = chunk >> 2;
    int k = chunk & 3;
    int t0 = seg * tchunk;

    const f32x4* src = (const f32x4*)(br + (size_t)(k * B_SZ + b) * T_SZ * C_SZ);
    int c4 = threadIdx.x;
    f32x4 acc = (f32x4)(0.f);
#pragma unroll 4
    for (int t = t0; t < t0 + tchunk; ++t) {
        acc += src[(size_t)t * (C_SZ / 4) + c4];
    }
    f32x4* dst = (f32x4*)(part + ((size_t)seg * 32 + chunk) * C_SZ);
    dst[c4] = acc;
}

// ---------------------------------------------------------------------------
// Kernel 2: finish pooling + h = tanh(pooled @ w_proj^T) * w_out -> partial
// logits. grid = 256 blocks (chunk = bid>>3, hgroup = bid&7).
// ---------------------------------------------------------------------------
__global__ void proj_logits(const float* __restrict__ part,
                            const float* __restrict__ w_proj,
                            const float* __restrict__ w_out,
                            float* __restrict__ logits_part,
                            int tseg) {
    __shared__ float pooled[C_SZ];
    __shared__ float red[32];
    int bid   = blockIdx.x;
    int chunk = bid >> 3;
    int hg    = bid & 7;
    int tid   = threadIdx.x;

    f32x4 acc = (f32x4)(0.f);
    for (int seg = 0; seg < tseg; ++seg) {
        acc += ((const f32x4*)(part + ((size_t)seg * 32 + chunk) * C_SZ))[tid];
    }
    const float inv = 1.0f / (float)T_SZ;
    ((f32x4*)pooled)[tid] = acc * inv;
    __syncthreads();

    int h   = hg * 32 + (tid >> 3);
    int sub = tid & 7;
    const f32x4* wrow = (const f32x4*)(w_proj + (size_t)h * C_SZ);
    const f32x4* pl   = (const f32x4*)pooled;
    float dot = 0.f;
#pragma unroll 8
    for (int j = 0; j < 32; ++j) {
        int c4 = sub * 32 + j;
        f32x4 w = wrow[c4];
        f32x4 p = pl[c4];
        f32x4 m = w * p;
        dot += m.x + m.y + m.z + m.w;
    }
    dot += __shfl_xor(dot, 1, 64);
    dot += __shfl_xor(dot, 2, 64);
    dot += __shfl_xor(dot, 4, 64);
    if (sub == 0) red[tid >> 3] = tanhf(dot) * w_out[h];
    __syncthreads();
    if (tid == 0) {
        float s = 0.f;
        for (int i = 0; i < 32; ++i) s += red[i];
        logits_part[chunk * 8 + hg] = s;
    }
}

// ---------------------------------------------------------------------------
// Kernel 3 (fast path): weights, then blend from the int8 copy.
// Thread n owns output f32x4 dst[n] (lane-linear -> fully-coalesced NT
// stores, 1 KiB/wave full lines — round-4/5 lesson: the strided 16B NT
// stores were partial-line WC flushes and collapsed write BW).
// Per iter: one u32 (4 int8) load per branch, 4 B/lane coalesced.
// ---------------------------------------------------------------------------
__global__ void mix_q(const u32* __restrict__ qs,
                      const float* __restrict__ logits_part,
                      float* __restrict__ out) {
    __shared__ float lp[256];
    __shared__ float lg[32];
    __shared__ float wgt[B_SZ][4];
    int tid = threadIdx.x;
    compute_weights(logits_part, lp, lg, wgt, tid);

    const size_t n4tot = (size_t)B_SZ * T_SZ * C_SZ / 4;    // 4,194,304
    const size_t btc4  = (size_t)T_SZ * C_SZ / 4;           // 2^19
    f32x4* dst = (f32x4*)out;
    for (size_t n = (size_t)blockIdx.x * blockDim.x + tid;
         n < n4tot;
         n += (size_t)gridDim.x * blockDim.x) {
        int b = (int)(n >> 19);
        size_t r = n & (btc4 - 1);
        float w0 = wgt[b][0] * QSCALE;
        float w1 = wgt[b][1] * QSCALE;
        float w2 = wgt[b][2] * QSCALE;
        float w3 = wgt[b][3] * QSCALE;
        u32 x0 = qs[((size_t)(0 * B_SZ + b) << 19) + r];
        u32 x1 = qs[((size_t)(1 * B_SZ + b) << 19) + r];
        u32 x2 = qs[((size_t)(2 * B_SZ + b) << 19) + r];
        u32 x3 = qs[((size_t)(3 * B_SZ + b) << 19) + r];
        f32x4 o;
#pragma unroll
        for (int i = 0; i < 4; ++i) {
            float e0 = (float)(signed char)((x0 >> (8 * i)) & 0xFF);
            float e1 = (float)(signed char)((x1 >> (8 * i)) & 0xFF);
            float e2 = (float)(signed char)((x2 >> (8 * i)) & 0xFF);
            float e3 = (float)(signed char)((x3 >> (8 * i)) & 0xFF);
            o[i] = w0 * e0 + w1 * e1 + w2 * e2 + w3 * e3;
        }
        __builtin_nontemporal_store(o, &dst[n]);
    }
}

// ---------------------------------------------------------------------------
// Kernel 3 (fallback): fp32 blend straight from branches (round-3 version).
// ---------------------------------------------------------------------------
__global__ void mix_kernel(const float* __restrict__ br,
                           const float* __restrict__ logits_part,
                           float* __restrict__ out) {
    __shared__ float lp[256];
    __shared__ float lg[32];
    __shared__ float wgt[B_SZ][4];
    int tid = threadIdx.x;
    compute_weights(logits_part, lp, lg, wgt, tid);

    const size_t n4total = (size_t)B_SZ * T_SZ * C_SZ / 4;
    const size_t btc4 = (size_t)T_SZ * C_SZ / 4;            // 2^19
    const f32x4* src = (const f32x4*)br;
    f32x4* dst = (f32x4*)out;
    for (size_t n = (size_t)blockIdx.x * blockDim.x + tid;
         n < n4total;
         n += (size_t)gridDim.x * blockDim.x) {
        int b = (int)(n >> 19);
        size_t r = n & (btc4 - 1);
        float w0 = wgt[b][0], w1 = wgt[b][1], w2 = wgt[b][2], w3 = wgt[b][3];
        f32x4 v0 = src[((size_t)(0 * B_SZ + b)) * btc4 + r];
        f32x4 v1 = src[((size_t)(1 * B_SZ + b)) * btc4 + r];
        f32x4 v2 = src[((size_t)(2 * B_SZ + b)) * btc4 + r];
        f32x4 v3 = src[((size_t)(3 * B_SZ + b)) * btc4 + r];
        f32x4 o = w0 * v0 + w1 * v1 + w2 * v2 + w3 * v3;
        __builtin_nontemporal_store(o, &dst[n]);
    }
}

extern "C" void kernel_launch(void* const* d_in, const int* in_sizes, int n_in,
                              void* d_out, int out_size, void* d_ws, size_t ws_size,
                              hipStream_t stream) {
    const float* branches = (const float*)d_in[0];
    const float* w_proj   = (const float*)d_in[1];
    const float* w_out    = (const float*)d_in[2];
    float* out = (float*)d_out;

    const size_t qs_words = (size_t)4 * B_SZ * T_SZ * (C_SZ / 4);  // 64 MiB
    const size_t part_need = (size_t)32 * 32 * C_SZ;               // tseg=32 partials
    size_t fast_need = qs_words * sizeof(u32) + (part_need + 256) * sizeof(float);

    if (ws_size >= fast_need) {
        int tseg = 32, tchunk = T_SZ / tseg;
        u32*   qs          = (u32*)d_ws;
        float* part        = (float*)(qs + qs_words);
        float* logits_part = part + part_need;

        pool_quant<<<tseg * 32, 256, 0, stream>>>(branches, part, qs, tchunk);
        proj_logits<<<256, 256, 0, stream>>>(part, w_proj, w_out, logits_part, tseg);
        mix_q<<<2048, 256, 0, stream>>>(qs, logits_part, out);
    } else {
        float* ws = (float*)d_ws;
        int tseg = 32;
        while (tseg > 1 &&
               ((size_t)tseg * 32 * C_SZ + 256) * sizeof(float) > ws_size)
            tseg >>= 1;
        int tchunk = T_SZ / tseg;
        float* part        = ws;
        float* logits_part = ws + (size_t)tseg * 32 * C_SZ;

        pool_partial<<<tseg * 32, 256, 0, stream>>>(branches, part, tchunk);
        proj_logits<<<256, 256, 0, stream>>>(part, w_proj, w_out, logits_part, tseg);
        mix_kernel<<<2048, 256, 0, stream>>>(branches, logits_part, out);
    }
}